// Round 10
// baseline (212.656 us; speedup 1.0000x reference)
//
#include <hip/hip_runtime.h>
#include <hip/hip_bf16.h>

#define DIMF 128
#define KNBR 32
#define NH 4
#define DH 32
#define RADIUS 0.3f
#define CB 8       // centers per main block (topk TC == attn CB == 8)
#define CAND 256   // max candidates/center (Poisson max lambda~118)
#define PPB 32     // points per nearest block

#define NEAR_BLOCKS 512    // N/PPB
#define PACK_BLOCKS 60     // 4+4+4+16+16 float4-transposes + 16 Wk-pack
#define PREP_BLOCKS (NEAR_BLOCKS + PACK_BLOCKS)

typedef unsigned long long u64t;

// float4-granular transpose tile: out4[a*BI + b] = in4[b*AI + a]
__device__ __forceinline__ void tr4_tile(const float4* __restrict__ in4, float4* __restrict__ out4,
                                         int AI, int BI, int a0, int b0, int t, char* smem) {
    float4(*tile)[33] = (float4(*)[33])smem;
    int tx = t & 31, ty = t >> 5;  // 32 x 8
    for (int r = ty; r < 32; r += 8) tile[r][tx] = in4[(long)(b0 + r) * AI + a0 + tx];
    __syncthreads();
    for (int r = ty; r < 32; r += 8) out4[(long)(a0 + r) * BI + b0 + tx] = tile[tx][r];
}

// ================= kernel 1: prep (nearest-argmin + pdata + weight packs) ===
__global__ __launch_bounds__(256, 2) void prep_kernel(
    const float* __restrict__ xyz, const int* __restrict__ idxc,
    const float* __restrict__ Wq, const float* __restrict__ Wv,
    const float* __restrict__ Wo, const float* __restrict__ W1,
    const float* __restrict__ W2, const float* __restrict__ Wk,
    float4* __restrict__ qp4, float4* __restrict__ vp4, float4* __restrict__ op4,
    float4* __restrict__ w1p4, float4* __restrict__ w2p4, float4* __restrict__ kp4,
    float4* __restrict__ pdata, int* __restrict__ bestm, int N, int M) {
    __shared__ __align__(16) char smem[16896];
    int b = blockIdx.x, t = threadIdx.x;

    if (b < NEAR_BLOCKS) {
        // ---------- pdata for this block's 32 points (consumed by main topk) -
        if (t < PPB) {
            int n0 = b * PPB + t;
            float x = xyz[3 * n0], y = xyz[3 * n0 + 1], z = xyz[3 * n0 + 2];
            pdata[n0] = make_float4(x, y, z, (x * x + y * y) + z * z);
        }
        // ---------- nearest-center argmin, 32 pts/block, 8 lanes/pt ----------
        // Key: s = |c|^2 - 2 c.p (== d2 - |p|^2; same argmin ordering, sqrt
        // monotone). Duplicate centers give exactly equal s -> lexicographic
        // (s, index) min == np.argmin first-occurrence. stride-8 interleave:
        // conflict-free LDS.
        float4* cds = (float4*)smem;
        int pt = t >> 3, q = t & 7;
        int n = b * PPB + pt;
        float px = xyz[3 * n], py = xyz[3 * n + 1], pz = xyz[3 * n + 2];
        float bd0 = INFINITY, bd1 = INFINITY;
        int bm0 = 0, bm1 = 0;
        for (int c0 = 0; c0 < M; c0 += 1024) {
            __syncthreads();
            for (int i = t; i < 1024; i += 256) {
                int ic = idxc[c0 + i];
                float cx = xyz[3 * ic], cy = xyz[3 * ic + 1], cz = xyz[3 * ic + 2];
                cds[i] = make_float4(-2.0f * cx, -2.0f * cy, -2.0f * cz,
                                     (cx * cx + cy * cy) + cz * cz);
            }
            __syncthreads();
#pragma unroll 8
            for (int i = 0; i < 64; ++i) {
                int ci0 = q + (2 * i) * 8, ci1 = q + (2 * i + 1) * 8;
                float4 ca = cds[ci0];
                float4 cb = cds[ci1];
                float sa = fmaf(ca.x, px, fmaf(ca.y, py, fmaf(ca.z, pz, ca.w)));
                float sb = fmaf(cb.x, px, fmaf(cb.y, py, fmaf(cb.z, pz, cb.w)));
                if (sa < bd0) { bd0 = sa; bm0 = c0 + ci0; }  // ascending scan keeps lowest idx
                if (sb < bd1) { bd1 = sb; bm1 = c0 + ci1; }
            }
        }
        if (bd1 < bd0 || (bd1 == bd0 && bm1 < bm0)) { bd0 = bd1; bm0 = bm1; }
#pragma unroll
        for (int o = 1; o < 8; o <<= 1) {
            float obd = __shfl_xor(bd0, o);
            int obm = __shfl_xor(bm0, o);
            if (obd < bd0 || (obd == bd0 && obm < bm0)) { bd0 = obd; bm0 = obm; }
        }
        if (q == 0) bestm[n] = bm0;
    } else {
        // ---------- weight packs (float4-quad layouts for the attn GEMMs) ----
        int pk = b - NEAR_BLOCKS;
        if (pk < 4) {
            tr4_tile((const float4*)Wq, qp4, 32, 128, 0, pk * 32, t, smem);
        } else if (pk < 8) {
            tr4_tile((const float4*)Wv, vp4, 32, 128, 0, (pk - 4) * 32, t, smem);
        } else if (pk < 12) {
            tr4_tile((const float4*)Wo, op4, 32, 128, 0, (pk - 8) * 32, t, smem);
        } else if (pk < 28) {
            tr4_tile((const float4*)W1, w1p4, 32, 512, 0, (pk - 12) * 32, t, smem);
        } else if (pk < 44) {
            int i = pk - 28;
            tr4_tile((const float4*)W2, w2p4, 128, 128, (i >> 2) * 32, (i & 3) * 32, t, smem);
        } else {
            // Wk pack: kp4[q*128+j] = {Wk[(4q+r)*128+j]}_{r=0..3}
            int idx = (pk - 44) * 256 + t;
            int q = idx >> 7, j = idx & 127;
            float4 w;
            w.x = Wk[(long)(4 * q + 0) * DIMF + j];
            w.y = Wk[(long)(4 * q + 1) * DIMF + j];
            w.z = Wk[(long)(4 * q + 2) * DIMF + j];
            w.w = Wk[(long)(4 * q + 3) * DIMF + j];
            kp4[q * DIMF + j] = w;
        }
    }
}

// ================= kernel 2: main — topk + attention + FFN, 8 centers/block =
__global__ __launch_bounds__(256, 2) void main_kernel(
    const float* __restrict__ xyz, const float* __restrict__ feats,
    const int* __restrict__ idxc, const float4* __restrict__ pdata,
    const float4* __restrict__ qp4, const float4* __restrict__ kp4,
    const float4* __restrict__ vp4, const float4* __restrict__ op4,
    const float* __restrict__ bo, const float* __restrict__ g1,
    const float* __restrict__ be1, const float* __restrict__ g2,
    const float* __restrict__ be2, const float4* __restrict__ w1p4,
    const float* __restrict__ b1f, const float4* __restrict__ w2p4,
    const float* __restrict__ b2f, float* __restrict__ cfin, int N) {
    __shared__ __align__(16) char smem[32768];
    __shared__ int nbrl[CB][KNBR];
    __shared__ int cnt[CB];

    int t = threadIdx.x;
    int m0 = blockIdx.x * CB;

    // ======== phase 1: radius top-K for centers m0..m0+7 (pdata scan) ========
    {
        u64t(*cand)[CAND] = (u64t(*)[CAND])smem;
        if (t < CB) cnt[t] = 0;
        __syncthreads();
        float nx[CB], ny[CB], nz[CB], cw[CB];
#pragma unroll
        for (int tc = 0; tc < CB; ++tc) {
            int ic = idxc[m0 + tc];
            float cx = xyz[3 * ic], cy = xyz[3 * ic + 1], cz = xyz[3 * ic + 2];
            cw[tc] = (cx * cx + cy * cy) + cz * cz;
            nx[tc] = -2.0f * cx; ny[tc] = -2.0f * cy; nz[tc] = -2.0f * cz;
        }
        const float R2 = RADIUS * RADIUS;
#pragma unroll 4
        for (int n = t; n < N; n += 256) {
            float4 p = pdata[n];
            float rhs = R2 - p.w;  // s < rhs  <=>  s + pw < R2
#pragma unroll
            for (int tc = 0; tc < CB; ++tc) {
                float s = fmaf(nx[tc], p.x, fmaf(ny[tc], p.y, fmaf(nz[tc], p.z, cw[tc])));
                if (s < rhs) {
                    int pos = atomicAdd(&cnt[tc], 1);
                    if (pos < CAND)
                        cand[tc][pos] = (((u64t)__float_as_uint(fmaxf(s + p.w, 0.0f))) << 32) | (unsigned)n;
                }
            }
        }
        __syncthreads();
        // wave w extracts centers w and w+4 via rank-select into LDS nbrl
        int w = t >> 6, lane = t & 63;
        for (int rep = 0; rep < 2; ++rep) {
            int cidx = w + rep * 4;
            int C = cnt[cidx] < CAND ? cnt[cidx] : CAND;
            const u64t* vc = cand[cidx];
            if (C <= 64) {
                u64t mykey = (lane < C) ? vc[lane] : ~0ull;
                int rank = 0;
                for (int j = 0; j < C; ++j) rank += (vc[j] < mykey) ? 1 : 0;
                if (lane < C && rank < KNBR) nbrl[cidx][rank] = (int)(mykey & 0xffffffffu);
                if (lane >= C && lane < KNBR) nbrl[cidx][lane] = -1;
            } else {
                u64t mykey[4];
                int myrank[4];
#pragma unroll
                for (int s = 0; s < 4; ++s) {
                    int i = s * 64 + lane;
                    mykey[s] = (i < C) ? vc[i] : ~0ull;
                    myrank[s] = 0;
                }
                for (int j = 0; j < C; ++j) {
                    u64t kj = vc[j];
#pragma unroll
                    for (int s = 0; s < 4; ++s) myrank[s] += (kj < mykey[s]) ? 1 : 0;
                }
#pragma unroll
                for (int s = 0; s < 4; ++s) {
                    int i = s * 64 + lane;
                    if (i < C && myrank[s] < KNBR) nbrl[cidx][myrank[s]] = (int)(mykey[s] & 0xffffffffu);
                }
            }
        }
    }
    __syncthreads();  // cand reads done; smem becomes attn buffers

    // ======== phase 2: attention + FFN (R7 structure) ========
    float(*cf)[DIMF] = (float(*)[DIMF])smem;
    float(*cf2)[DIMF] = (float(*)[DIMF])(smem + 4096);
    float(*S1)[4 * DIMF] = (float(*)[4 * DIMF])(smem + 8192);
    float(*S2)[DIMF] = (float(*)[DIMF])(smem + 24576);
    float(*S3)[DIMF] = (float(*)[DIMF])(smem + 28672);

    int lane127 = t & 127;
    int cg = (t >> 7) * 4;
    int c8 = t >> 5, k32 = t & 31;

    {
        int ic = idxc[m0 + c8];
        *(float4*)&cf[c8][k32 * 4] = *(const float4*)&feats[(long)ic * DIMF + k32 * 4];
    }
    __syncthreads();

    // ---- A: q = Wq @ cf (scaled) -> S2 ----
    {
        float acc[4] = {0.f, 0.f, 0.f, 0.f};
        for (int jj = 0; jj < 32; ++jj) {
            float4 w = qp4[jj * DIMF + lane127];
#pragma unroll
            for (int cc = 0; cc < 4; ++cc) {
                float4 x = *(const float4*)&cf[cg + cc][jj * 4];
                acc[cc] += w.x * x.x + w.y * x.y + w.z * x.z + w.w * x.w;
            }
        }
#pragma unroll
        for (int cc = 0; cc < 4; ++cc) S2[cg + cc][lane127] = acc[cc] * 0.17677669529663687f;
    }
    __syncthreads();

    // ---- B: qw[c][h][j] -> S1 ----
    {
        int j = lane127, hs = t >> 7;
#pragma unroll
        for (int hh = 0; hh < 2; ++hh) {
            int h = hs * 2 + hh;
            float acc[8] = {0.f, 0.f, 0.f, 0.f, 0.f, 0.f, 0.f, 0.f};
            for (int d4 = 0; d4 < 8; ++d4) {
                float4 w = kp4[(h * 8 + d4) * DIMF + j];
#pragma unroll
                for (int c = 0; c < 8; ++c) {
                    float4 qv = *(const float4*)&S2[c][h * DH + d4 * 4];
                    acc[c] += qv.x * w.x + qv.y * w.y + qv.z * w.z + qv.w * w.w;
                }
            }
#pragma unroll
            for (int c = 0; c < 8; ++c) S1[c][h * DIMF + j] = acc[c];
        }
    }
    __syncthreads();

    // ---- C: logits + softmax -> S3 ----
    {
        int ni = nbrl[c8][k32];
        const float* nrow = feats + (long)(ni < 0 ? 0 : ni) * DIMF;
        float lg[4] = {0.f, 0.f, 0.f, 0.f};
        for (int jj = 0; jj < 32; ++jj) {
            float4 f = *(const float4*)&nrow[jj * 4];
#pragma unroll
            for (int h = 0; h < 4; ++h) {
                float4 qwv = *(const float4*)&S1[c8][h * DIMF + jj * 4];
                lg[h] += f.x * qwv.x + f.y * qwv.y + f.z * qwv.z + f.w * qwv.w;
            }
        }
        if (ni < 0) { lg[0] = -1e9f; lg[1] = -1e9f; lg[2] = -1e9f; lg[3] = -1e9f; }
#pragma unroll
        for (int h = 0; h < 4; ++h) {
            float mx = lg[h];
            for (int o = 16; o; o >>= 1) mx = fmaxf(mx, __shfl_xor(mx, o, 32));
            float e = expf(lg[h] - mx);
            float s = e;
            for (int o = 16; o; o >>= 1) s += __shfl_xor(s, o, 32);
            S3[c8][h * KNBR + k32] = e / s;
        }
    }
    __syncthreads();

    // ---- D: pool -> S1 (overwrite qw) ----
    {
        int j4 = k32 * 4;
        float a0x = 0.f, a0y = 0.f, a0z = 0.f, a0w = 0.f;
        float a1x = 0.f, a1y = 0.f, a1z = 0.f, a1w = 0.f;
        float a2x = 0.f, a2y = 0.f, a2z = 0.f, a2w = 0.f;
        float a3x = 0.f, a3y = 0.f, a3z = 0.f, a3w = 0.f;
        for (int k = 0; k < KNBR; ++k) {
            int ni = nbrl[c8][k];
            const float* nrow = feats + (long)(ni < 0 ? 0 : ni) * DIMF;
            float4 f = *(const float4*)&nrow[j4];
            float w0 = S3[c8][0 * KNBR + k], w1 = S3[c8][1 * KNBR + k];
            float w2 = S3[c8][2 * KNBR + k], w3 = S3[c8][3 * KNBR + k];
            a0x += w0 * f.x; a0y += w0 * f.y; a0z += w0 * f.z; a0w += w0 * f.w;
            a1x += w1 * f.x; a1y += w1 * f.y; a1z += w1 * f.z; a1w += w1 * f.w;
            a2x += w2 * f.x; a2y += w2 * f.y; a2z += w2 * f.z; a2w += w2 * f.w;
            a3x += w3 * f.x; a3y += w3 * f.y; a3z += w3 * f.z; a3w += w3 * f.w;
        }
        __syncthreads();
        *(float4*)&S1[c8][0 * DIMF + j4] = make_float4(a0x, a0y, a0z, a0w);
        *(float4*)&S1[c8][1 * DIMF + j4] = make_float4(a1x, a1y, a1z, a1w);
        *(float4*)&S1[c8][2 * DIMF + j4] = make_float4(a2x, a2y, a2z, a2w);
        *(float4*)&S1[c8][3 * DIMF + j4] = make_float4(a3x, a3y, a3z, a3w);
    }
    __syncthreads();

    // ---- E: updin -> S2 ----
    {
        int i = lane127, h = i >> 5, d = i & 31;
        float acc[4] = {0.f, 0.f, 0.f, 0.f};
        for (int jj = 0; jj < 32; ++jj) {
            float4 w = vp4[jj * DIMF + i];
#pragma unroll
            for (int cc = 0; cc < 4; ++cc) {
                float4 pv = *(const float4*)&S1[cg + cc][h * DIMF + jj * 4];
                acc[cc] += w.x * pv.x + w.y * pv.y + w.z * pv.z + w.w * pv.w;
            }
        }
        __syncthreads();
#pragma unroll
        for (int cc = 0; cc < 4; ++cc) S2[cg + cc][d * NH + h] = acc[cc];
    }
    __syncthreads();

    // ---- F: upd = Wo @ updin + bo -> S3 ----
    {
        int i = lane127;
        float acc[4] = {0.f, 0.f, 0.f, 0.f};
        for (int jj = 0; jj < 32; ++jj) {
            float4 w = op4[jj * DIMF + i];
#pragma unroll
            for (int cc = 0; cc < 4; ++cc) {
                float4 x = *(const float4*)&S2[cg + cc][jj * 4];
                acc[cc] += w.x * x.x + w.y * x.y + w.z * x.z + w.w * x.w;
            }
        }
        float b = bo[i];
        __syncthreads();
#pragma unroll
        for (int cc = 0; cc < 4; ++cc) S3[cg + cc][i] = acc[cc] + b;
    }
    __syncthreads();

    // ---- G: LN1 + residual -> cf2 ----
    {
        int i4 = k32 * 4;
        float4 u = *(const float4*)&S3[c8][i4];
        float s = ((u.x + u.y) + u.z) + u.w;
        for (int o = 16; o; o >>= 1) s += __shfl_xor(s, o, 32);
        float mu = s * (1.0f / DIMF);
        float d0 = u.x - mu, d1 = u.y - mu, d2 = u.z - mu, d3 = u.w - mu;
        float vs = ((d0 * d0 + d1 * d1) + d2 * d2) + d3 * d3;
        for (int o = 16; o; o >>= 1) vs += __shfl_xor(vs, o, 32);
        float rs = 1.0f / sqrtf(vs * (1.0f / DIMF) + 1e-5f);
        float4 g = *(const float4*)&g1[i4];
        float4 b = *(const float4*)&be1[i4];
        float4 base = *(const float4*)&cf[c8][i4];
        float4 r;
        r.x = base.x + d0 * rs * g.x + b.x;
        r.y = base.y + d1 * rs * g.y + b.y;
        r.z = base.z + d2 * rs * g.z + b.z;
        r.w = base.w + d3 * rs * g.w + b.w;
        *(float4*)&cf2[c8][i4] = r;
    }
    __syncthreads();

    // ---- H: FFN1 relu -> S1 ----
    {
        int u0 = lane127;
        float acc[4][4];
#pragma unroll
        for (int p = 0; p < 4; ++p)
#pragma unroll
            for (int cc = 0; cc < 4; ++cc) acc[p][cc] = 0.f;
        for (int jj = 0; jj < 32; ++jj) {
            float4 x[4];
#pragma unroll
            for (int cc = 0; cc < 4; ++cc) x[cc] = *(const float4*)&cf2[cg + cc][jj * 4];
#pragma unroll
            for (int p = 0; p < 4; ++p) {
                float4 w = w1p4[jj * 512 + u0 + p * DIMF];
#pragma unroll
                for (int cc = 0; cc < 4; ++cc)
                    acc[p][cc] += w.x * x[cc].x + w.y * x[cc].y + w.z * x[cc].z + w.w * x[cc].w;
            }
        }
#pragma unroll
        for (int p = 0; p < 4; ++p) {
            float b = b1f[u0 + p * DIMF];
#pragma unroll
            for (int cc = 0; cc < 4; ++cc)
                S1[cg + cc][u0 + p * DIMF] = fmaxf(acc[p][cc] + b, 0.f);
        }
    }
    __syncthreads();

    // ---- I: FFN2 -> S3 ----
    {
        int i = lane127;
        float acc[4] = {0.f, 0.f, 0.f, 0.f};
        for (int uu = 0; uu < 128; ++uu) {
            float4 w = w2p4[uu * DIMF + i];
#pragma unroll
            for (int cc = 0; cc < 4; ++cc) {
                float4 hh = *(const float4*)&S1[cg + cc][uu * 4];
                acc[cc] += w.x * hh.x + w.y * hh.y + w.z * hh.z + w.w * hh.w;
            }
        }
        float b = b2f[i];
        __syncthreads();
#pragma unroll
        for (int cc = 0; cc < 4; ++cc) S3[cg + cc][i] = acc[cc] + b;
    }
    __syncthreads();

    // ---- J: LN2 + residual -> cfin ----
    {
        int i4 = k32 * 4;
        float4 u = *(const float4*)&S3[c8][i4];
        float s = ((u.x + u.y) + u.z) + u.w;
        for (int o = 16; o; o >>= 1) s += __shfl_xor(s, o, 32);
        float mu = s * (1.0f / DIMF);
        float d0 = u.x - mu, d1 = u.y - mu, d2 = u.z - mu, d3 = u.w - mu;
        float vs = ((d0 * d0 + d1 * d1) + d2 * d2) + d3 * d3;
        for (int o = 16; o; o >>= 1) vs += __shfl_xor(vs, o, 32);
        float rs = 1.0f / sqrtf(vs * (1.0f / DIMF) + 1e-5f);
        float4 g = *(const float4*)&g2[i4];
        float4 b = *(const float4*)&be2[i4];
        float4 base = *(const float4*)&cf2[c8][i4];
        float4 r;
        r.x = base.x + d0 * rs * g.x + b.x;
        r.y = base.y + d1 * rs * g.y + b.y;
        r.z = base.z + d2 * rs * g.z + b.z;
        r.w = base.w + d3 * rs * g.w + b.w;
        *(float4*)&cfin[(long)(m0 + c8) * DIMF + i4] = r;
    }
}

// ================= kernel 3: out = feats + cfin[bestm] ======================
__global__ __launch_bounds__(256) void out_kernel(const float4* __restrict__ feats4,
                                                  const float* __restrict__ cfin,
                                                  const int* __restrict__ bestm,
                                                  float4* __restrict__ out4, int total) {
    int idx = blockIdx.x * 256 + threadIdx.x;
    if (idx >= total) return;
    int n = idx >> 5, c = idx & 31;
    const float4* cf4 = (const float4*)cfin;
    float4 f = feats4[idx];
    float4 g = cf4[(long)bestm[n] * 32 + c];
    out4[idx] = make_float4(f.x + g.x, f.y + g.y, f.z + g.z, f.w + g.w);
}

extern "C" void kernel_launch(void* const* d_in, const int* in_sizes, int n_in,
                              void* d_out, int out_size, void* d_ws, size_t ws_size,
                              hipStream_t stream) {
    const float* xyz = (const float*)d_in[0];
    const float* feats = (const float*)d_in[1];
    const int* idxc = (const int*)d_in[2];
    const float* Wq = (const float*)d_in[3];
    const float* Wk = (const float*)d_in[4];
    const float* Wv = (const float*)d_in[5];
    const float* Wo = (const float*)d_in[6];
    const float* bo = (const float*)d_in[7];
    const float* g1 = (const float*)d_in[8];
    const float* be1 = (const float*)d_in[9];
    const float* g2 = (const float*)d_in[10];
    const float* be2 = (const float*)d_in[11];
    const float* W1 = (const float*)d_in[12];
    const float* b1f = (const float*)d_in[13];
    const float* W2 = (const float*)d_in[14];
    const float* b2f = (const float*)d_in[15];

    int N = in_sizes[0] / 3;
    int M = in_sizes[2];

    char* ws = (char*)d_ws;
    size_t off = 0;
    float* cfin = (float*)(ws + off); off += (size_t)M * DIMF * 4;
    int* bestm = (int*)(ws + off); off += (size_t)N * 4;
    float4* pdata = (float4*)(ws + off); off += (size_t)N * 16;
    float4* qp4 = (float4*)(ws + off); off += (size_t)DIMF * DIMF * 4;
    float4* vp4 = (float4*)(ws + off); off += (size_t)DIMF * DIMF * 4;
    float4* op4 = (float4*)(ws + off); off += (size_t)DIMF * DIMF * 4;
    float4* kp4 = (float4*)(ws + off); off += (size_t)DIMF * DIMF * 4;
    float4* w1p4 = (float4*)(ws + off); off += (size_t)4 * DIMF * DIMF * 4;
    float4* w2p4 = (float4*)(ws + off); off += (size_t)4 * DIMF * DIMF * 4;
    (void)ws_size; (void)n_in; (void)out_size;

    prep_kernel<<<PREP_BLOCKS, 256, 0, stream>>>(
        xyz, idxc, Wq, Wv, Wo, W1, W2, Wk,
        qp4, vp4, op4, w1p4, w2p4, kp4, pdata, bestm, N, M);
    main_kernel<<<M / CB, 256, 0, stream>>>(
        xyz, feats, idxc, pdata, qp4, kp4, vp4, op4, bo, g1, be1, g2, be2,
        w1p4, b1f, w2p4, b2f, cfin, N);
    out_kernel<<<(N * DIMF / 4 + 255) / 256, 256, 0, stream>>>(
        (const float4*)feats, cfin, bestm, (float4*)d_out, N * DIMF / 4);
}